// Round 6
// baseline (896.999 us; speedup 1.0000x reference)
//
#include <hip/hip_runtime.h>
#include <math.h>

#define N_NODES 50000
#define N_EDGES 800000
#define N_TOT   850000   // edges + self loops

// ----------------------------- utility kernels -----------------------------
__global__ void zero_int_kernel(int* p, int n) {
    int i = blockIdx.x * blockDim.x + threadIdx.x;
    if (i < n) p[i] = 0;
}

__global__ void copy_int_kernel(const int* a, int* b, int n) {
    int i = blockIdx.x * blockDim.x + threadIdx.x;
    if (i < n) b[i] = a[i];
}

// ----------------------------- CSR build -----------------------------------
// NOTE: harness delivers integer inputs as int32 (int64 in reference is cast).
__global__ void deg_hist_kernel(const int* __restrict__ ei, int* __restrict__ deg) {
    int e = blockIdx.x * blockDim.x + threadIdx.x;
    if (e >= N_TOT) return;
    int dst = (e < N_EDGES) ? ei[N_EDGES + e] : (e - N_EDGES);
    atomicAdd(&deg[dst], 1);
}

// single block, 256 threads: exclusive scan of deg[0..N_NODES) -> off[0..N_NODES]
__global__ void scan_offsets_kernel(const int* __restrict__ deg, int* __restrict__ off) {
    __shared__ int sa[256], sb[256];
    const int n = N_NODES;
    int t = threadIdx.x;
    const int chunk = (n + 255) / 256;
    int base = t * chunk;
    int s = 0;
    for (int i = 0; i < chunk; i++) {
        int idx = base + i;
        if (idx < n) s += deg[idx];
    }
    sa[t] = s;
    __syncthreads();
    int* src_ = sa; int* dst_ = sb;
    for (int d = 1; d < 256; d <<= 1) {
        dst_[t] = (t >= d) ? (src_[t - d] + src_[t]) : src_[t];
        __syncthreads();
        int* tmp = src_; src_ = dst_; dst_ = tmp;
    }
    int inc  = src_[t];
    int excl = inc - s;
    int run = excl;
    for (int i = 0; i < chunk; i++) {
        int idx = base + i;
        if (idx < n) { off[idx] = run; run += deg[idx]; }
    }
    if (t == 255) off[n] = src_[255];
}

__global__ void fill_csr_kernel(const int* __restrict__ ei, int* __restrict__ cursor,
                                int* __restrict__ csr_src) {
    int e = blockIdx.x * blockDim.x + threadIdx.x;
    if (e >= N_TOT) return;
    int src, dst;
    if (e < N_EDGES) { src = ei[e]; dst = ei[N_EDGES + e]; }
    else             { src = dst = e - N_EDGES; }
    int pos = atomicAdd(&cursor[dst], 1);
    csr_src[pos] = src;
}

// ----------------------------- GEMM: h = x @ W ------------------------------
// block = 256 threads, 32 nodes per block. W is [Cin, Cout] row-major.
// Register tiling: each thread owns OCP=4 output channels x NACC nodes.
template<int Cin, int Cout>
__global__ void gemm_tile_kernel(const float* __restrict__ x, const float* __restrict__ W,
                                 float* __restrict__ h) {
    constexpr int OCP  = 4;
    constexpr int OCT  = Cout / OCP;     // oc-threads: 64 / 32 / 8
    constexpr int NG   = 256 / OCT;      // node groups: 4 / 8 / 32
    constexpr int NACC = 32 / NG;        // nodes per thread: 8 / 4 / 1
    __shared__ float xs[32][Cin];
    int n0  = blockIdx.x * 32;
    int tid = threadIdx.x;
    // coalesced float4 staging of 32 node rows
    for (int i = tid; i < 32 * Cin / 4; i += 256) {
        int n = i / (Cin / 4), k4 = i % (Cin / 4);
        int gn = n0 + n;
        float4 v = (gn < N_NODES) ? ((const float4*)(x + (size_t)gn * Cin))[k4]
                                  : make_float4(0.f, 0.f, 0.f, 0.f);
        ((float4*)xs[n])[k4] = v;
    }
    __syncthreads();
    int oct  = tid % OCT;
    int nsub = tid / OCT;
    float acc[NACC][OCP];
#pragma unroll
    for (int i = 0; i < NACC; i++)
#pragma unroll
        for (int j = 0; j < OCP; j++) acc[i][j] = 0.f;

#pragma unroll 4
    for (int k = 0; k < Cin; k++) {
        float wv[OCP];
#pragma unroll
        for (int j = 0; j < OCP; j++) wv[j] = W[(size_t)k * Cout + oct + j * OCT];
#pragma unroll
        for (int i = 0; i < NACC; i++) {
            float xv = xs[nsub * NACC + i][k];
#pragma unroll
            for (int j = 0; j < OCP; j++) acc[i][j] += xv * wv[j];
        }
    }
#pragma unroll
    for (int i = 0; i < NACC; i++) {
        int gn = n0 + nsub * NACC + i;
        if (gn < N_NODES) {
#pragma unroll
            for (int j = 0; j < OCP; j++)
                h[(size_t)gn * Cout + oct + j * OCT] = acc[i][j];
        }
    }
}

// ------------------- per-node attention logits al_s, al_d -------------------
template<int H, int C>
__global__ void attn_logits_kernel(const float* __restrict__ h, const float* __restrict__ a_src,
                                   const float* __restrict__ a_dst, float* __restrict__ al_s,
                                   float* __restrict__ al_d) {
    int i = blockIdx.x * blockDim.x + threadIdx.x;   // (n, head)
    if (i >= N_NODES * H) return;
    int n = i / H, head = i % H;
    const float4* hp = (const float4*)(h + (size_t)n * H * C + head * C);
    const float4* as4 = (const float4*)(a_src + head * C);
    const float4* ad4 = (const float4*)(a_dst + head * C);
    float ss = 0.f, sd = 0.f;
#pragma unroll
    for (int c = 0; c < C / 4; c++) {
        float4 v = hp[c], a = as4[c], d = ad4[c];
        ss += v.x * a.x + v.y * a.y + v.z * a.z + v.w * a.w;
        sd += v.x * d.x + v.y * d.y + v.z * d.z + v.w * d.w;
    }
    al_s[i] = ss;
    al_d[i] = sd;
}

// ------------------------- GAT softmax + aggregation ------------------------
// One group of G = H*C/4 lanes per node; each lane owns 4 output channels
// (float4) of head = g/SUB where SUB = G/H lanes serve each head.
// Phase 1: lane reduces ONLY its own head, edges strided by SUB; butterfly
//   over log2(SUB) stages puts (m,s) for head h exactly in head-h lanes.
// Phase 2: uniform edge loop, batches of 8. Every lane recomputes its own
//   head's weight (redundant across SUB lanes but overlapped with gather
//   latency). NO cross-lane ops in the loop: h-gather addresses depend only
//   on the batch's csr_src loads, so 8 row-gathers stay in flight per wave.
template<int H, int C, bool RELU>
__launch_bounds__(256, 8)
__global__ void gat_agg_kernel(const float* __restrict__ h, const float* __restrict__ al_s,
                               const float* __restrict__ al_d, const int* __restrict__ off,
                               const int* __restrict__ csr_src, const float* __restrict__ bias,
                               float* __restrict__ out) {
    constexpr int HC  = H * C;
    constexpr int G   = HC / 4;    // lanes per node (64 / 32 / 8)
    constexpr int SUB = G / H;     // lanes per head = edge-parallel width
    constexpr int NPW = 64 / G;    // nodes per wave
    constexpr int NPB = 4 * NPW;   // nodes per 256-thread block

    int tid  = threadIdx.x;
    int wid  = tid >> 6;
    int lane = tid & 63;
    int gi   = lane / G;           // node slot within wave
    int g    = lane % G;           // lane within node group
    int node = blockIdx.x * NPB + wid * NPW + gi;
    if (node >= N_NODES) return;

    int head = g / SUB;            // this lane's head
    int es   = g % SUB;            // edge-stride slot within head group
    int r0 = off[node], r1 = off[node + 1];
    float ald = al_d[node * H + head];

    // ---- phase 1: online softmax for OWN head, edges strided by SUB ----
    float m = -INFINITY, s = 0.f;
    for (int j = r0 + es; j < r1; j += SUB) {
        int src = csr_src[j];
        float e = al_s[src * H + head] + ald;
        e = (e > 0.f) ? e : 0.2f * e;
        float M = fmaxf(m, e);
        s = s * __expf(m - M) + __expf(e - M);
        m = M;
    }
#pragma unroll
    for (int k = 1; k < SUB; k <<= 1) {
        float om = __shfl_xor(m, k, 64);
        float os = __shfl_xor(s, k, 64);
        float M = fmaxf(m, om);
        float S;
        if (M == -INFINITY) S = 0.f;   // guard NaN from (-inf) - (-inf)
        else S = s * __expf(m - M) + os * __expf(om - M);
        m = M; s = S;
    }
    float inv_s = 1.f / s;             // s >= 1: every node has a self loop

    // ---- phase 2: uniform edge loop, batches of 8, no cross-lane ops ----
    const float4* hv4 = (const float4*)h;
    float4 acc = ((const float4*)bias)[g];
    int j0 = r0;
    for (; j0 + 8 <= r1; j0 += 8) {
        int srcs[8];
#pragma unroll
        for (int u = 0; u < 8; u++) srcs[u] = csr_src[j0 + u];
#pragma unroll
        for (int u = 0; u < 8; u++) {
            float e = al_s[srcs[u] * H + head] + ald;
            e = (e > 0.f) ? e : 0.2f * e;
            float we = __expf(e - m) * inv_s;
            float4 hv = hv4[(size_t)srcs[u] * (HC / 4) + g];
            acc.x += we * hv.x; acc.y += we * hv.y;
            acc.z += we * hv.z; acc.w += we * hv.w;
        }
    }
    for (; j0 < r1; j0++) {
        int src = csr_src[j0];
        float e = al_s[src * H + head] + ald;
        e = (e > 0.f) ? e : 0.2f * e;
        float we = __expf(e - m) * inv_s;
        float4 hv = hv4[(size_t)src * (HC / 4) + g];
        acc.x += we * hv.x; acc.y += we * hv.y;
        acc.z += we * hv.z; acc.w += we * hv.w;
    }
    if (RELU) {
        acc.x = fmaxf(acc.x, 0.f); acc.y = fmaxf(acc.y, 0.f);
        acc.z = fmaxf(acc.z, 0.f); acc.w = fmaxf(acc.w, 0.f);
    }
    ((float4*)(out + (size_t)node * HC))[g] = acc;
}

// ------------------------------- launcher -----------------------------------
extern "C" void kernel_launch(void* const* d_in, const int* in_sizes, int n_in,
                              void* d_out, int out_size, void* d_ws, size_t ws_size,
                              hipStream_t stream) {
    const float* x   = (const float*)d_in[0];
    const int*   ei  = (const int*)d_in[1];   // harness casts int64 -> int32
    const float* W1  = (const float*)d_in[2];
    const float* as1 = (const float*)d_in[3];
    const float* ad1 = (const float*)d_in[4];
    const float* b1  = (const float*)d_in[5];
    const float* W2  = (const float*)d_in[6];
    const float* as2 = (const float*)d_in[7];
    const float* ad2 = (const float*)d_in[8];
    const float* b2  = (const float*)d_in[9];
    const float* W3  = (const float*)d_in[10];
    const float* as3 = (const float*)d_in[11];
    const float* ad3 = (const float*)d_in[12];
    const float* b3  = (const float*)d_in[13];
    const float* W4  = (const float*)d_in[14];
    const float* as4 = (const float*)d_in[15];
    const float* ad4 = (const float*)d_in[16];
    const float* b4  = (const float*)d_in[17];

    char* ws = (char*)d_ws;
    size_t o = 0;
    auto alloc = [&](size_t bytes) -> void* {
        void* p = ws + o;
        o = (o + bytes + 255) & ~(size_t)255;
        return p;
    };
    float* feat_a  = (float*)alloc((size_t)N_NODES * 256 * 4);  // 51.2 MB
    float* feat_b  = (float*)alloc((size_t)N_NODES * 32 * 4);   // 6.4 MB
    float* h_buf   = (float*)alloc((size_t)N_NODES * 256 * 4);  // 51.2 MB
    float* al_s    = (float*)alloc((size_t)N_NODES * 8 * 4);
    float* al_d    = (float*)alloc((size_t)N_NODES * 8 * 4);
    int*   deg     = (int*)alloc((size_t)(N_NODES + 1) * 4);
    int*   off     = (int*)alloc((size_t)(N_NODES + 1) * 4);
    int*   cursor  = (int*)alloc((size_t)N_NODES * 4);
    int*   csr_src = (int*)alloc((size_t)N_TOT * 4);

    const int TPB = 256;
    int nb_nodes = (N_NODES + TPB - 1) / TPB;
    int nb_edges = (N_TOT + TPB - 1) / TPB;
    int nb_gemm  = (N_NODES + 31) / 32;

    // ---- CSR build (by dst) ----
    zero_int_kernel<<<nb_nodes, TPB, 0, stream>>>(deg, N_NODES);
    deg_hist_kernel<<<nb_edges, TPB, 0, stream>>>(ei, deg);
    scan_offsets_kernel<<<1, TPB, 0, stream>>>(deg, off);
    copy_int_kernel<<<nb_nodes, TPB, 0, stream>>>(off, cursor, N_NODES);
    fill_csr_kernel<<<nb_edges, TPB, 0, stream>>>(ei, cursor, csr_src);

    // nodes per block for gat_agg: NPB = 4 * 64 / (H*C/4)
    auto agg_blocks = [](int hc) { return (N_NODES * (hc / 4) + 255) / 256; };

    // ---- Layer 1: 128 -> (8 heads x 32), ReLU ----
    gemm_tile_kernel<128, 256><<<nb_gemm, TPB, 0, stream>>>(x, W1, h_buf);
    attn_logits_kernel<8, 32><<<(N_NODES * 8 + TPB - 1) / TPB, TPB, 0, stream>>>(h_buf, as1, ad1, al_s, al_d);
    gat_agg_kernel<8, 32, true><<<agg_blocks(256), TPB, 0, stream>>>(h_buf, al_s, al_d, off, csr_src, b1, feat_a);

    // ---- Layer 2: 256 -> 32, 1 head ----
    gemm_tile_kernel<256, 32><<<nb_gemm, TPB, 0, stream>>>(feat_a, W2, h_buf);
    attn_logits_kernel<1, 32><<<(N_NODES + TPB - 1) / TPB, TPB, 0, stream>>>(h_buf, as2, ad2, al_s, al_d);
    gat_agg_kernel<1, 32, false><<<agg_blocks(32), TPB, 0, stream>>>(h_buf, al_s, al_d, off, csr_src, b2, feat_b);

    // ---- Layer 3: 32 -> (8 heads x 32), ReLU ----
    gemm_tile_kernel<32, 256><<<nb_gemm, TPB, 0, stream>>>(feat_b, W3, h_buf);
    attn_logits_kernel<8, 32><<<(N_NODES * 8 + TPB - 1) / TPB, TPB, 0, stream>>>(h_buf, as3, ad3, al_s, al_d);
    gat_agg_kernel<8, 32, true><<<agg_blocks(256), TPB, 0, stream>>>(h_buf, al_s, al_d, off, csr_src, b3, feat_a);

    // ---- Layer 4: 256 -> 128, 1 head ----
    gemm_tile_kernel<256, 128><<<nb_gemm, TPB, 0, stream>>>(feat_a, W4, h_buf);
    attn_logits_kernel<1, 128><<<(N_NODES + TPB - 1) / TPB, TPB, 0, stream>>>(h_buf, as4, ad4, al_s, al_d);
    gat_agg_kernel<1, 128, false><<<agg_blocks(128), TPB, 0, stream>>>(h_buf, al_s, al_d, off, csr_src, b4, (float*)d_out);
}

// Round 7
// 797.779 us; speedup vs baseline: 1.1244x; 1.1244x over previous
//
#include <hip/hip_runtime.h>
#include <math.h>

#define N_NODES 50000
#define N_EDGES 800000
#define N_TOT   850000   // edges + self loops

// ---------------------------- bf16 pack/unpack ------------------------------
__device__ __forceinline__ unsigned int pack_bf16x2(float a, float b) {
    unsigned ua = __float_as_uint(a);
    unsigned ub = __float_as_uint(b);
    ua += 0x7fff + ((ua >> 16) & 1);   // round-to-nearest-even
    ub += 0x7fff + ((ub >> 16) & 1);
    return (ua >> 16) | (ub & 0xffff0000u);
}
__device__ __forceinline__ float bf16_lo(unsigned u) { return __uint_as_float(u << 16); }
__device__ __forceinline__ float bf16_hi(unsigned u) { return __uint_as_float(u & 0xffff0000u); }

// ----------------------------- utility kernels -----------------------------
__global__ void zero_int_kernel(int* p, int n) {
    int i = blockIdx.x * blockDim.x + threadIdx.x;
    if (i < n) p[i] = 0;
}

__global__ void copy_int_kernel(const int* a, int* b, int n) {
    int i = blockIdx.x * blockDim.x + threadIdx.x;
    if (i < n) b[i] = a[i];
}

// ----------------------------- CSR build -----------------------------------
// NOTE: harness delivers integer inputs as int32 (int64 in reference is cast).
__global__ void deg_hist_kernel(const int* __restrict__ ei, int* __restrict__ deg) {
    int e = blockIdx.x * blockDim.x + threadIdx.x;
    if (e >= N_TOT) return;
    int dst = (e < N_EDGES) ? ei[N_EDGES + e] : (e - N_EDGES);
    atomicAdd(&deg[dst], 1);
}

// single block, 256 threads: exclusive scan of deg[0..N_NODES) -> off[0..N_NODES]
__global__ void scan_offsets_kernel(const int* __restrict__ deg, int* __restrict__ off) {
    __shared__ int sa[256], sb[256];
    const int n = N_NODES;
    int t = threadIdx.x;
    const int chunk = (n + 255) / 256;
    int base = t * chunk;
    int s = 0;
    for (int i = 0; i < chunk; i++) {
        int idx = base + i;
        if (idx < n) s += deg[idx];
    }
    sa[t] = s;
    __syncthreads();
    int* src_ = sa; int* dst_ = sb;
    for (int d = 1; d < 256; d <<= 1) {
        dst_[t] = (t >= d) ? (src_[t - d] + src_[t]) : src_[t];
        __syncthreads();
        int* tmp = src_; src_ = dst_; dst_ = tmp;
    }
    int inc  = src_[t];
    int excl = inc - s;
    int run = excl;
    for (int i = 0; i < chunk; i++) {
        int idx = base + i;
        if (idx < n) { off[idx] = run; run += deg[idx]; }
    }
    if (t == 255) off[n] = src_[255];
}

__global__ void fill_csr_kernel(const int* __restrict__ ei, int* __restrict__ cursor,
                                int* __restrict__ csr_src) {
    int e = blockIdx.x * blockDim.x + threadIdx.x;
    if (e >= N_TOT) return;
    int src, dst;
    if (e < N_EDGES) { src = ei[e]; dst = ei[N_EDGES + e]; }
    else             { src = dst = e - N_EDGES; }
    int pos = atomicAdd(&cursor[dst], 1);
    csr_src[pos] = src;
}

// ----------------------------- GEMM: h = x @ W -> bf16 ----------------------
// block = 256 threads, 32 nodes per block. W is [Cin, Cout] row-major fp32.
// Each thread owns 4 CONTIGUOUS output channels (one float4 W load per k)
// x NACC nodes. Output packed to bf16 (2 u32 per node per thread, coalesced).
template<int Cin, int Cout>
__global__ void gemm_tile_kernel(const float* __restrict__ x, const float* __restrict__ W,
                                 unsigned short* __restrict__ hb) {
    constexpr int OCP  = 4;
    constexpr int OCT  = Cout / OCP;     // oc-threads: 64 / 32 / 8
    constexpr int NG   = 256 / OCT;      // node groups: 4 / 8 / 32
    constexpr int NACC = 32 / NG;        // nodes per thread: 8 / 4 / 1
    __shared__ float xs[32][Cin];
    int n0  = blockIdx.x * 32;
    int tid = threadIdx.x;
    // coalesced float4 staging of 32 node rows
    for (int i = tid; i < 32 * Cin / 4; i += 256) {
        int n = i / (Cin / 4), k4 = i % (Cin / 4);
        int gn = n0 + n;
        float4 v = (gn < N_NODES) ? ((const float4*)(x + (size_t)gn * Cin))[k4]
                                  : make_float4(0.f, 0.f, 0.f, 0.f);
        ((float4*)xs[n])[k4] = v;
    }
    __syncthreads();
    int oct  = tid % OCT;
    int nsub = tid / OCT;
    float acc[NACC][OCP];
#pragma unroll
    for (int i = 0; i < NACC; i++)
#pragma unroll
        for (int j = 0; j < OCP; j++) acc[i][j] = 0.f;

#pragma unroll 4
    for (int k = 0; k < Cin; k++) {
        float4 wv = ((const float4*)(W + (size_t)k * Cout))[oct];
#pragma unroll
        for (int i = 0; i < NACC; i++) {
            float xv = xs[nsub * NACC + i][k];
            acc[i][0] += xv * wv.x; acc[i][1] += xv * wv.y;
            acc[i][2] += xv * wv.z; acc[i][3] += xv * wv.w;
        }
    }
#pragma unroll
    for (int i = 0; i < NACC; i++) {
        int gn = n0 + nsub * NACC + i;
        if (gn < N_NODES) {
            uint2 p;
            p.x = pack_bf16x2(acc[i][0], acc[i][1]);
            p.y = pack_bf16x2(acc[i][2], acc[i][3]);
            ((uint2*)hb)[((size_t)gn * Cout) / 4 + oct] = p;
        }
    }
}

// ------------------- per-node attention logits al_s, al_d -------------------
template<int H, int C>
__global__ void attn_logits_kernel(const unsigned short* __restrict__ hb,
                                   const float* __restrict__ a_src,
                                   const float* __restrict__ a_dst, float* __restrict__ al_s,
                                   float* __restrict__ al_d) {
    int i = blockIdx.x * blockDim.x + threadIdx.x;   // (n, head)
    if (i >= N_NODES * H) return;
    int n = i / H, head = i % H;
    const uint2* hp = (const uint2*)(hb + (size_t)n * H * C + head * C);
    const float4* as4 = (const float4*)(a_src + head * C);
    const float4* ad4 = (const float4*)(a_dst + head * C);
    float ss = 0.f, sd = 0.f;
#pragma unroll
    for (int c = 0; c < C / 4; c++) {
        uint2 q = hp[c];
        float v0 = bf16_lo(q.x), v1 = bf16_hi(q.x), v2 = bf16_lo(q.y), v3 = bf16_hi(q.y);
        float4 a = as4[c], d = ad4[c];
        ss += v0 * a.x + v1 * a.y + v2 * a.z + v3 * a.w;
        sd += v0 * d.x + v1 * d.y + v2 * d.z + v3 * d.w;
    }
    al_s[i] = ss;
    al_d[i] = sd;
}

// ------------------------- GAT softmax + aggregation ------------------------
// One group of G = H*C/4 lanes per node; each lane owns 4 output channels
// (bf16 payload: one uint2 = 8 B per lane per edge; a row = G*8 B in one
// wave instruction). head = g/SUB, SUB = G/H lanes per head.
// Phase 1: lane reduces ONLY its own head, edges strided by SUB; butterfly
//   over log2(SUB) stages puts (m,s) for head h exactly in head-h lanes.
// Phase 2: uniform edge loop, batches of 8; no cross-lane ops; gather
//   addresses depend only on the batch's csr_src loads.
template<int H, int C, bool RELU>
__launch_bounds__(256, 8)
__global__ void gat_agg_kernel(const unsigned short* __restrict__ hb,
                               const float* __restrict__ al_s,
                               const float* __restrict__ al_d, const int* __restrict__ off,
                               const int* __restrict__ csr_src, const float* __restrict__ bias,
                               float* __restrict__ out) {
    constexpr int HC  = H * C;
    constexpr int G   = HC / 4;    // lanes per node (64 / 32 / 8)
    constexpr int SUB = G / H;     // lanes per head = edge-parallel width
    constexpr int NPW = 64 / G;    // nodes per wave
    constexpr int NPB = 4 * NPW;   // nodes per 256-thread block

    int tid  = threadIdx.x;
    int wid  = tid >> 6;
    int lane = tid & 63;
    int gi   = lane / G;           // node slot within wave
    int g    = lane % G;           // lane within node group
    int node = blockIdx.x * NPB + wid * NPW + gi;
    if (node >= N_NODES) return;

    int head = g / SUB;            // this lane's head
    int es   = g % SUB;            // edge-stride slot within head group
    int r0 = off[node], r1 = off[node + 1];
    float ald = al_d[node * H + head];

    // ---- phase 1: online softmax for OWN head, edges strided by SUB ----
    float m = -INFINITY, s = 0.f;
    for (int j = r0 + es; j < r1; j += SUB) {
        int src = csr_src[j];
        float e = al_s[src * H + head] + ald;
        e = (e > 0.f) ? e : 0.2f * e;
        float M = fmaxf(m, e);
        s = s * __expf(m - M) + __expf(e - M);
        m = M;
    }
#pragma unroll
    for (int k = 1; k < SUB; k <<= 1) {
        float om = __shfl_xor(m, k, 64);
        float os = __shfl_xor(s, k, 64);
        float M = fmaxf(m, om);
        float S;
        if (M == -INFINITY) S = 0.f;   // guard NaN from (-inf) - (-inf)
        else S = s * __expf(m - M) + os * __expf(om - M);
        m = M; s = S;
    }
    float inv_s = 1.f / s;             // s >= 1: every node has a self loop

    // ---- phase 2: uniform edge loop, batches of 8, no cross-lane ops ----
    const uint2* hb2 = (const uint2*)hb;
    float4 acc = ((const float4*)bias)[g];
    int j0 = r0;
    for (; j0 + 8 <= r1; j0 += 8) {
        int srcs[8];
#pragma unroll
        for (int u = 0; u < 8; u++) srcs[u] = csr_src[j0 + u];
#pragma unroll
        for (int u = 0; u < 8; u++) {
            float e = al_s[srcs[u] * H + head] + ald;
            e = (e > 0.f) ? e : 0.2f * e;
            float we = __expf(e - m) * inv_s;
            uint2 q = hb2[(size_t)srcs[u] * (HC / 4) + g];
            acc.x += we * bf16_lo(q.x); acc.y += we * bf16_hi(q.x);
            acc.z += we * bf16_lo(q.y); acc.w += we * bf16_hi(q.y);
        }
    }
    for (; j0 < r1; j0++) {
        int src = csr_src[j0];
        float e = al_s[src * H + head] + ald;
        e = (e > 0.f) ? e : 0.2f * e;
        float we = __expf(e - m) * inv_s;
        uint2 q = hb2[(size_t)src * (HC / 4) + g];
        acc.x += we * bf16_lo(q.x); acc.y += we * bf16_hi(q.x);
        acc.z += we * bf16_lo(q.y); acc.w += we * bf16_hi(q.y);
    }
    if (RELU) {
        acc.x = fmaxf(acc.x, 0.f); acc.y = fmaxf(acc.y, 0.f);
        acc.z = fmaxf(acc.z, 0.f); acc.w = fmaxf(acc.w, 0.f);
    }
    ((float4*)(out + (size_t)node * HC))[g] = acc;
}

// ------------------------------- launcher -----------------------------------
extern "C" void kernel_launch(void* const* d_in, const int* in_sizes, int n_in,
                              void* d_out, int out_size, void* d_ws, size_t ws_size,
                              hipStream_t stream) {
    const float* x   = (const float*)d_in[0];
    const int*   ei  = (const int*)d_in[1];   // harness casts int64 -> int32
    const float* W1  = (const float*)d_in[2];
    const float* as1 = (const float*)d_in[3];
    const float* ad1 = (const float*)d_in[4];
    const float* b1  = (const float*)d_in[5];
    const float* W2  = (const float*)d_in[6];
    const float* as2 = (const float*)d_in[7];
    const float* ad2 = (const float*)d_in[8];
    const float* b2  = (const float*)d_in[9];
    const float* W3  = (const float*)d_in[10];
    const float* as3 = (const float*)d_in[11];
    const float* ad3 = (const float*)d_in[12];
    const float* b3  = (const float*)d_in[13];
    const float* W4  = (const float*)d_in[14];
    const float* as4 = (const float*)d_in[15];
    const float* ad4 = (const float*)d_in[16];
    const float* b4  = (const float*)d_in[17];

    char* ws = (char*)d_ws;
    size_t o = 0;
    auto alloc = [&](size_t bytes) -> void* {
        void* p = ws + o;
        o = (o + bytes + 255) & ~(size_t)255;
        return p;
    };
    float*          feat_a  = (float*)alloc((size_t)N_NODES * 256 * 4);  // 51.2 MB
    float*          feat_b  = (float*)alloc((size_t)N_NODES * 32 * 4);   // 6.4 MB
    unsigned short* h_buf   = (unsigned short*)alloc((size_t)N_NODES * 256 * 2);  // 25.6 MB bf16
    float*          al_s    = (float*)alloc((size_t)N_NODES * 8 * 4);
    float*          al_d    = (float*)alloc((size_t)N_NODES * 8 * 4);
    int*            deg     = (int*)alloc((size_t)(N_NODES + 1) * 4);
    int*            off     = (int*)alloc((size_t)(N_NODES + 1) * 4);
    int*            cursor  = (int*)alloc((size_t)N_NODES * 4);
    int*            csr_src = (int*)alloc((size_t)N_TOT * 4);

    const int TPB = 256;
    int nb_nodes = (N_NODES + TPB - 1) / TPB;
    int nb_edges = (N_TOT + TPB - 1) / TPB;
    int nb_gemm  = (N_NODES + 31) / 32;

    // ---- CSR build (by dst) ----
    zero_int_kernel<<<nb_nodes, TPB, 0, stream>>>(deg, N_NODES);
    deg_hist_kernel<<<nb_edges, TPB, 0, stream>>>(ei, deg);
    scan_offsets_kernel<<<1, TPB, 0, stream>>>(deg, off);
    copy_int_kernel<<<nb_nodes, TPB, 0, stream>>>(off, cursor, N_NODES);
    fill_csr_kernel<<<nb_edges, TPB, 0, stream>>>(ei, cursor, csr_src);

    // nodes per block for gat_agg: NPB = 4 * 64 / (H*C/4)
    auto agg_blocks = [](int hc) { return (N_NODES * (hc / 4) + 255) / 256; };

    // ---- Layer 1: 128 -> (8 heads x 32), ReLU ----
    gemm_tile_kernel<128, 256><<<nb_gemm, TPB, 0, stream>>>(x, W1, h_buf);
    attn_logits_kernel<8, 32><<<(N_NODES * 8 + TPB - 1) / TPB, TPB, 0, stream>>>(h_buf, as1, ad1, al_s, al_d);
    gat_agg_kernel<8, 32, true><<<agg_blocks(256), TPB, 0, stream>>>(h_buf, al_s, al_d, off, csr_src, b1, feat_a);

    // ---- Layer 2: 256 -> 32, 1 head ----
    gemm_tile_kernel<256, 32><<<nb_gemm, TPB, 0, stream>>>(feat_a, W2, h_buf);
    attn_logits_kernel<1, 32><<<(N_NODES + TPB - 1) / TPB, TPB, 0, stream>>>(h_buf, as2, ad2, al_s, al_d);
    gat_agg_kernel<1, 32, false><<<agg_blocks(32), TPB, 0, stream>>>(h_buf, al_s, al_d, off, csr_src, b2, feat_b);

    // ---- Layer 3: 32 -> (8 heads x 32), ReLU ----
    gemm_tile_kernel<32, 256><<<nb_gemm, TPB, 0, stream>>>(feat_b, W3, h_buf);
    attn_logits_kernel<8, 32><<<(N_NODES * 8 + TPB - 1) / TPB, TPB, 0, stream>>>(h_buf, as3, ad3, al_s, al_d);
    gat_agg_kernel<8, 32, true><<<agg_blocks(256), TPB, 0, stream>>>(h_buf, al_s, al_d, off, csr_src, b3, feat_a);

    // ---- Layer 4: 256 -> 128, 1 head ----
    gemm_tile_kernel<256, 128><<<nb_gemm, TPB, 0, stream>>>(feat_a, W4, h_buf);
    attn_logits_kernel<1, 128><<<(N_NODES + TPB - 1) / TPB, TPB, 0, stream>>>(h_buf, as4, ad4, al_s, al_d);
    gat_agg_kernel<1, 128, false><<<agg_blocks(128), TPB, 0, stream>>>(h_buf, al_s, al_d, off, csr_src, b4, (float*)d_out);
}

// Round 8
// 729.801 us; speedup vs baseline: 1.2291x; 1.0931x over previous
//
#include <hip/hip_runtime.h>
#include <math.h>

#define N_NODES 50000
#define N_EDGES 800000
#define N_TOT   850000   // edges + self loops

// ---------------------------- bf16 pack/unpack ------------------------------
__device__ __forceinline__ unsigned int pack_bf16x2(float a, float b) {
    unsigned ua = __float_as_uint(a);
    unsigned ub = __float_as_uint(b);
    ua += 0x7fff + ((ua >> 16) & 1);   // round-to-nearest-even
    ub += 0x7fff + ((ub >> 16) & 1);
    return (ua >> 16) | (ub & 0xffff0000u);
}
__device__ __forceinline__ float bf16_lo(unsigned u) { return __uint_as_float(u << 16); }
__device__ __forceinline__ float bf16_hi(unsigned u) { return __uint_as_float(u & 0xffff0000u); }

// ----------------------------- utility kernels -----------------------------
__global__ void zero_int_kernel(int* p, int n) {
    int i = blockIdx.x * blockDim.x + threadIdx.x;
    if (i < n) p[i] = 0;
}

__global__ void copy_int_kernel(const int* a, int* b, int n) {
    int i = blockIdx.x * blockDim.x + threadIdx.x;
    if (i < n) b[i] = a[i];
}

// ----------------------------- CSR build -----------------------------------
// NOTE: harness delivers integer inputs as int32 (int64 in reference is cast).
__global__ void deg_hist_kernel(const int* __restrict__ ei, int* __restrict__ deg) {
    int e = blockIdx.x * blockDim.x + threadIdx.x;
    if (e >= N_TOT) return;
    int dst = (e < N_EDGES) ? ei[N_EDGES + e] : (e - N_EDGES);
    atomicAdd(&deg[dst], 1);
}

// single block, 256 threads: exclusive scan of deg[0..N_NODES) -> off[0..N_NODES]
__global__ void scan_offsets_kernel(const int* __restrict__ deg, int* __restrict__ off) {
    __shared__ int sa[256], sb[256];
    const int n = N_NODES;
    int t = threadIdx.x;
    const int chunk = (n + 255) / 256;
    int base = t * chunk;
    int s = 0;
    for (int i = 0; i < chunk; i++) {
        int idx = base + i;
        if (idx < n) s += deg[idx];
    }
    sa[t] = s;
    __syncthreads();
    int* src_ = sa; int* dst_ = sb;
    for (int d = 1; d < 256; d <<= 1) {
        dst_[t] = (t >= d) ? (src_[t - d] + src_[t]) : src_[t];
        __syncthreads();
        int* tmp = src_; src_ = dst_; dst_ = tmp;
    }
    int inc  = src_[t];
    int excl = inc - s;
    int run = excl;
    for (int i = 0; i < chunk; i++) {
        int idx = base + i;
        if (idx < n) { off[idx] = run; run += deg[idx]; }
    }
    if (t == 255) off[n] = src_[255];
}

__global__ void fill_csr_kernel(const int* __restrict__ ei, int* __restrict__ cursor,
                                int* __restrict__ csr_src) {
    int e = blockIdx.x * blockDim.x + threadIdx.x;
    if (e >= N_TOT) return;
    int src, dst;
    if (e < N_EDGES) { src = ei[e]; dst = ei[N_EDGES + e]; }
    else             { src = dst = e - N_EDGES; }
    int pos = atomicAdd(&cursor[dst], 1);
    csr_src[pos] = src;
}

// ------------------ fused GEMM + attention logits ---------------------------
// block = 256 threads, 32 nodes per block. W fp32 [Cin, Cout] row-major.
// Thread owns 4 CONTIGUOUS output channels x NACC nodes; h written bf16.
// Epilogue: head h's C channels live in R = C/4 consecutive aligned lanes ->
// shfl_xor reduction computes al_s/al_d in-kernel (no separate logits pass).
template<int Cin, int Cout, int H, int C, bool IN_BF16>
__global__ void gemm_fused_kernel(const void* __restrict__ xin, const float* __restrict__ W,
                                  const float* __restrict__ a_src, const float* __restrict__ a_dst,
                                  unsigned short* __restrict__ hb,
                                  float* __restrict__ al_s, float* __restrict__ al_d) {
    constexpr int OCP  = 4;
    constexpr int OCT  = Cout / OCP;     // oc-threads: 64 / 32 / 8
    constexpr int NG   = 256 / OCT;      // node groups: 4 / 8 / 32
    constexpr int NACC = 32 / NG;        // nodes per thread: 8 / 4 / 1
    constexpr int R    = C / 4;          // lanes per head
    __shared__ float xs[32][Cin];
    int n0  = blockIdx.x * 32;
    int tid = threadIdx.x;
    // coalesced staging of 32 node rows (fp32 float4 or bf16 uint2 -> fp32 LDS)
    for (int i = tid; i < 32 * Cin / 4; i += 256) {
        int n = i / (Cin / 4), k4 = i % (Cin / 4);
        int gn = n0 + n;
        float4 v = make_float4(0.f, 0.f, 0.f, 0.f);
        if (gn < N_NODES) {
            if (IN_BF16) {
                uint2 q = ((const uint2*)((const unsigned short*)xin + (size_t)gn * Cin))[k4];
                v = make_float4(bf16_lo(q.x), bf16_hi(q.x), bf16_lo(q.y), bf16_hi(q.y));
            } else {
                v = ((const float4*)((const float*)xin + (size_t)gn * Cin))[k4];
            }
        }
        ((float4*)xs[n])[k4] = v;
    }
    __syncthreads();
    int oct  = tid % OCT;
    int nsub = tid / OCT;
    int head = oct / R;                  // this thread's head (channels 4-contig)
    int cin_head = (oct % R) * 4;        // channel offset within head
    float acc[NACC][OCP];
#pragma unroll
    for (int i = 0; i < NACC; i++)
#pragma unroll
        for (int j = 0; j < OCP; j++) acc[i][j] = 0.f;

#pragma unroll 4
    for (int k = 0; k < Cin; k++) {
        float4 wv = ((const float4*)(W + (size_t)k * Cout))[oct];
#pragma unroll
        for (int i = 0; i < NACC; i++) {
            float xv = xs[nsub * NACC + i][k];
            acc[i][0] += xv * wv.x; acc[i][1] += xv * wv.y;
            acc[i][2] += xv * wv.z; acc[i][3] += xv * wv.w;
        }
    }
    // load attention vectors for own 4 channels
    float4 av = ((const float4*)(a_src + head * C + cin_head))[0];
    float4 dv = ((const float4*)(a_dst + head * C + cin_head))[0];
#pragma unroll
    for (int i = 0; i < NACC; i++) {
        int gn = n0 + nsub * NACC + i;
        if (gn < N_NODES) {
            uint2 p;
            p.x = pack_bf16x2(acc[i][0], acc[i][1]);
            p.y = pack_bf16x2(acc[i][2], acc[i][3]);
            ((uint2*)hb)[((size_t)gn * Cout) / 4 + oct] = p;
        }
        // head-local logits reduction (R consecutive aligned lanes; gn uniform
        // within the shfl group, so no divergence hazard)
        float ps = acc[i][0] * av.x + acc[i][1] * av.y + acc[i][2] * av.z + acc[i][3] * av.w;
        float pd = acc[i][0] * dv.x + acc[i][1] * dv.y + acc[i][2] * dv.z + acc[i][3] * dv.w;
#pragma unroll
        for (int k = 1; k < R; k <<= 1) {
            ps += __shfl_xor(ps, k, 64);
            pd += __shfl_xor(pd, k, 64);
        }
        if ((oct % R) == 0 && gn < N_NODES) {
            al_s[gn * H + head] = ps;
            al_d[gn * H + head] = pd;
        }
    }
}

// ------------------------- GAT softmax + aggregation ------------------------
// One group of G = H*C/4 lanes per node; each lane owns 4 output channels
// (bf16 payload: one uint2 = 8 B per lane per edge). head = g/SUB.
// Phase 1: lane reduces ONLY its own head, edges strided by SUB; butterfly.
// Phase 2: uniform edge loop, batches of 8; no cross-lane ops; gather
//   addresses depend only on the batch's csr_src loads.
// OUT_BF16: intermediate feats written bf16; final layer writes fp32.
template<int H, int C, bool RELU, bool OUT_BF16>
__launch_bounds__(256, 8)
__global__ void gat_agg_kernel(const unsigned short* __restrict__ hb,
                               const float* __restrict__ al_s,
                               const float* __restrict__ al_d, const int* __restrict__ off,
                               const int* __restrict__ csr_src, const float* __restrict__ bias,
                               void* __restrict__ out) {
    constexpr int HC  = H * C;
    constexpr int G   = HC / 4;    // lanes per node (64 / 32 / 8)
    constexpr int SUB = G / H;     // lanes per head = edge-parallel width
    constexpr int NPW = 64 / G;    // nodes per wave
    constexpr int NPB = 4 * NPW;   // nodes per 256-thread block

    int tid  = threadIdx.x;
    int wid  = tid >> 6;
    int lane = tid & 63;
    int gi   = lane / G;           // node slot within wave
    int g    = lane % G;           // lane within node group
    int node = blockIdx.x * NPB + wid * NPW + gi;
    if (node >= N_NODES) return;

    int head = g / SUB;            // this lane's head
    int es   = g % SUB;            // edge-stride slot within head group
    int r0 = off[node], r1 = off[node + 1];
    float ald = al_d[node * H + head];

    // ---- phase 1: online softmax for OWN head, edges strided by SUB ----
    float m = -INFINITY, s = 0.f;
    for (int j = r0 + es; j < r1; j += SUB) {
        int src = csr_src[j];
        float e = al_s[src * H + head] + ald;
        e = (e > 0.f) ? e : 0.2f * e;
        float M = fmaxf(m, e);
        s = s * __expf(m - M) + __expf(e - M);
        m = M;
    }
#pragma unroll
    for (int k = 1; k < SUB; k <<= 1) {
        float om = __shfl_xor(m, k, 64);
        float os = __shfl_xor(s, k, 64);
        float M = fmaxf(m, om);
        float S;
        if (M == -INFINITY) S = 0.f;   // guard NaN from (-inf) - (-inf)
        else S = s * __expf(m - M) + os * __expf(om - M);
        m = M; s = S;
    }
    float inv_s = 1.f / s;             // s >= 1: every node has a self loop

    // ---- phase 2: uniform edge loop, batches of 8, no cross-lane ops ----
    const uint2* hb2 = (const uint2*)hb;
    float4 acc = ((const float4*)bias)[g];
    int j0 = r0;
    for (; j0 + 8 <= r1; j0 += 8) {
        int srcs[8];
#pragma unroll
        for (int u = 0; u < 8; u++) srcs[u] = csr_src[j0 + u];
#pragma unroll
        for (int u = 0; u < 8; u++) {
            float e = al_s[srcs[u] * H + head] + ald;
            e = (e > 0.f) ? e : 0.2f * e;
            float we = __expf(e - m) * inv_s;
            uint2 q = hb2[(size_t)srcs[u] * (HC / 4) + g];
            acc.x += we * bf16_lo(q.x); acc.y += we * bf16_hi(q.x);
            acc.z += we * bf16_lo(q.y); acc.w += we * bf16_hi(q.y);
        }
    }
    for (; j0 < r1; j0++) {
        int src = csr_src[j0];
        float e = al_s[src * H + head] + ald;
        e = (e > 0.f) ? e : 0.2f * e;
        float we = __expf(e - m) * inv_s;
        uint2 q = hb2[(size_t)src * (HC / 4) + g];
        acc.x += we * bf16_lo(q.x); acc.y += we * bf16_hi(q.x);
        acc.z += we * bf16_lo(q.y); acc.w += we * bf16_hi(q.y);
    }
    if (RELU) {
        acc.x = fmaxf(acc.x, 0.f); acc.y = fmaxf(acc.y, 0.f);
        acc.z = fmaxf(acc.z, 0.f); acc.w = fmaxf(acc.w, 0.f);
    }
    if (OUT_BF16) {
        uint2 p;
        p.x = pack_bf16x2(acc.x, acc.y);
        p.y = pack_bf16x2(acc.z, acc.w);
        ((uint2*)out)[(size_t)node * (HC / 4) + g] = p;
    } else {
        ((float4*)out)[(size_t)node * (HC / 4) + g] = acc;
    }
}

// ------------------------------- launcher -----------------------------------
extern "C" void kernel_launch(void* const* d_in, const int* in_sizes, int n_in,
                              void* d_out, int out_size, void* d_ws, size_t ws_size,
                              hipStream_t stream) {
    const float* x   = (const float*)d_in[0];
    const int*   ei  = (const int*)d_in[1];   // harness casts int64 -> int32
    const float* W1  = (const float*)d_in[2];
    const float* as1 = (const float*)d_in[3];
    const float* ad1 = (const float*)d_in[4];
    const float* b1  = (const float*)d_in[5];
    const float* W2  = (const float*)d_in[6];
    const float* as2 = (const float*)d_in[7];
    const float* ad2 = (const float*)d_in[8];
    const float* b2  = (const float*)d_in[9];
    const float* W3  = (const float*)d_in[10];
    const float* as3 = (const float*)d_in[11];
    const float* ad3 = (const float*)d_in[12];
    const float* b3  = (const float*)d_in[13];
    const float* W4  = (const float*)d_in[14];
    const float* as4 = (const float*)d_in[15];
    const float* ad4 = (const float*)d_in[16];
    const float* b4  = (const float*)d_in[17];

    char* ws = (char*)d_ws;
    size_t o = 0;
    auto alloc = [&](size_t bytes) -> void* {
        void* p = ws + o;
        o = (o + bytes + 255) & ~(size_t)255;
        return p;
    };
    unsigned short* feat_a  = (unsigned short*)alloc((size_t)N_NODES * 256 * 2); // 25.6 MB bf16
    unsigned short* feat_b  = (unsigned short*)alloc((size_t)N_NODES * 32 * 2);  // 3.2 MB bf16
    unsigned short* h_buf   = (unsigned short*)alloc((size_t)N_NODES * 256 * 2); // 25.6 MB bf16
    float*          al_s    = (float*)alloc((size_t)N_NODES * 8 * 4);
    float*          al_d    = (float*)alloc((size_t)N_NODES * 8 * 4);
    int*            deg     = (int*)alloc((size_t)(N_NODES + 1) * 4);
    int*            off     = (int*)alloc((size_t)(N_NODES + 1) * 4);
    int*            cursor  = (int*)alloc((size_t)N_NODES * 4);
    int*            csr_src = (int*)alloc((size_t)N_TOT * 4);

    const int TPB = 256;
    int nb_nodes = (N_NODES + TPB - 1) / TPB;
    int nb_edges = (N_TOT + TPB - 1) / TPB;
    int nb_gemm  = (N_NODES + 31) / 32;

    // ---- CSR build (by dst) ----
    zero_int_kernel<<<nb_nodes, TPB, 0, stream>>>(deg, N_NODES);
    deg_hist_kernel<<<nb_edges, TPB, 0, stream>>>(ei, deg);
    scan_offsets_kernel<<<1, TPB, 0, stream>>>(deg, off);
    copy_int_kernel<<<nb_nodes, TPB, 0, stream>>>(off, cursor, N_NODES);
    fill_csr_kernel<<<nb_edges, TPB, 0, stream>>>(ei, cursor, csr_src);

    auto agg_blocks = [](int hc) { return (N_NODES * (hc / 4) + 255) / 256; };

    // ---- Layer 1: 128 -> (8 heads x 32), ReLU ----
    gemm_fused_kernel<128, 256, 8, 32, false><<<nb_gemm, TPB, 0, stream>>>(x, W1, as1, ad1, h_buf, al_s, al_d);
    gat_agg_kernel<8, 32, true, true><<<agg_blocks(256), TPB, 0, stream>>>(h_buf, al_s, al_d, off, csr_src, b1, feat_a);

    // ---- Layer 2: 256 -> 32, 1 head ----
    gemm_fused_kernel<256, 32, 1, 32, true><<<nb_gemm, TPB, 0, stream>>>(feat_a, W2, as2, ad2, h_buf, al_s, al_d);
    gat_agg_kernel<1, 32, false, true><<<agg_blocks(32), TPB, 0, stream>>>(h_buf, al_s, al_d, off, csr_src, b2, feat_b);

    // ---- Layer 3: 32 -> (8 heads x 32), ReLU ----
    gemm_fused_kernel<32, 256, 8, 32, true><<<nb_gemm, TPB, 0, stream>>>(feat_b, W3, as3, ad3, h_buf, al_s, al_d);
    gat_agg_kernel<8, 32, true, true><<<agg_blocks(256), TPB, 0, stream>>>(h_buf, al_s, al_d, off, csr_src, b3, feat_a);

    // ---- Layer 4: 256 -> 128, 1 head ----
    gemm_fused_kernel<256, 128, 1, 128, true><<<nb_gemm, TPB, 0, stream>>>(feat_a, W4, as4, ad4, h_buf, al_s, al_d);
    gat_agg_kernel<1, 128, false, false><<<agg_blocks(128), TPB, 0, stream>>>(h_buf, al_s, al_d, off, csr_src, b4, d_out);
}

// Round 9
// 645.166 us; speedup vs baseline: 1.3903x; 1.1312x over previous
//
#include <hip/hip_runtime.h>
#include <math.h>

#define N_NODES 50000
#define N_EDGES 800000
#define N_TOT   850000   // edges + self loops
#define NSB     ((N_NODES + 255) / 256)   // scan blocks = 196

// ---------------------------- bf16 pack/unpack ------------------------------
__device__ __forceinline__ unsigned int pack_bf16x2(float a, float b) {
    unsigned ua = __float_as_uint(a);
    unsigned ub = __float_as_uint(b);
    ua += 0x7fff + ((ua >> 16) & 1);   // round-to-nearest-even
    ub += 0x7fff + ((ub >> 16) & 1);
    return (ua >> 16) | (ub & 0xffff0000u);
}
__device__ __forceinline__ float bf16_lo(unsigned u) { return __uint_as_float(u << 16); }
__device__ __forceinline__ float bf16_hi(unsigned u) { return __uint_as_float(u & 0xffff0000u); }

// ----------------------------- utility kernels -----------------------------
__global__ void zero_int_kernel(int* p, int n) {
    int i = blockIdx.x * blockDim.x + threadIdx.x;
    if (i < n) p[i] = 0;
}

// ----------------------------- CSR build -----------------------------------
// NOTE: harness delivers integer inputs as int32 (int64 in reference is cast).
__global__ void deg_hist_kernel(const int* __restrict__ ei, int* __restrict__ deg) {
    int e = blockIdx.x * blockDim.x + threadIdx.x;
    if (e >= N_TOT) return;
    int dst = (e < N_EDGES) ? ei[N_EDGES + e] : (e - N_EDGES);
    atomicAdd(&deg[dst], 1);
}

// pass 1: per-block exclusive scan (256 elems/block) + block sums
__global__ void block_scan_kernel(const int* __restrict__ deg, int* __restrict__ part,
                                  int* __restrict__ bsum) {
    __shared__ int tmp[256];
    int t = threadIdx.x;
    int i = blockIdx.x * 256 + t;
    int v = (i < N_NODES) ? deg[i] : 0;
    tmp[t] = v;
    __syncthreads();
    for (int d = 1; d < 256; d <<= 1) {
        int u = (t >= d) ? tmp[t - d] : 0;
        __syncthreads();
        tmp[t] += u;
        __syncthreads();
    }
    if (i < N_NODES) part[i] = tmp[t] - v;   // exclusive
    if (t == 255) bsum[blockIdx.x] = tmp[255];
}

// pass 2: single block scans the NSB block sums (NSB <= 256)
__global__ void scan_bsum_kernel(int* __restrict__ bsum) {
    __shared__ int tmp[256];
    int t = threadIdx.x;
    int v = (t < NSB) ? bsum[t] : 0;
    tmp[t] = v;
    __syncthreads();
    for (int d = 1; d < 256; d <<= 1) {
        int u = (t >= d) ? tmp[t - d] : 0;
        __syncthreads();
        tmp[t] += u;
        __syncthreads();
    }
    if (t < NSB) bsum[t] = tmp[t] - v;       // exclusive block offsets
}

// pass 3: final offsets; also initialize cursor (replaces copy kernel)
__global__ void finalize_off_kernel(const int* __restrict__ part, const int* __restrict__ bsum,
                                    int* __restrict__ off, int* __restrict__ cursor) {
    int i = blockIdx.x * 256 + threadIdx.x;
    if (i < N_NODES) {
        int o = part[i] + bsum[blockIdx.x];
        off[i] = o;
        cursor[i] = o;
    }
    if (i == 0) off[N_NODES] = N_TOT;        // total degree is a known constant
}

__global__ void fill_csr_kernel(const int* __restrict__ ei, int* __restrict__ cursor,
                                int* __restrict__ csr_src) {
    int e = blockIdx.x * blockDim.x + threadIdx.x;
    if (e >= N_TOT) return;
    int src, dst;
    if (e < N_EDGES) { src = ei[e]; dst = ei[N_EDGES + e]; }
    else             { src = dst = e - N_EDGES; }
    int pos = atomicAdd(&cursor[dst], 1);
    csr_src[pos] = src;
}

// ------------------ fused GEMM + attention logits ---------------------------
// block = 256 threads, 32 nodes per block. W fp32 [Cin, Cout] row-major.
// Thread owns 4 CONTIGUOUS output channels x NACC nodes; h written bf16.
// Epilogue: head h's C channels live in R = C/4 consecutive aligned lanes ->
// shfl_xor reduction computes al_s/al_d in-kernel (no separate logits pass).
template<int Cin, int Cout, int H, int C, bool IN_BF16>
__global__ void gemm_fused_kernel(const void* __restrict__ xin, const float* __restrict__ W,
                                  const float* __restrict__ a_src, const float* __restrict__ a_dst,
                                  unsigned short* __restrict__ hb,
                                  float* __restrict__ al_s, float* __restrict__ al_d) {
    constexpr int OCP  = 4;
    constexpr int OCT  = Cout / OCP;     // oc-threads: 64 / 32 / 8
    constexpr int NG   = 256 / OCT;      // node groups: 4 / 8 / 32
    constexpr int NACC = 32 / NG;        // nodes per thread: 8 / 4 / 1
    constexpr int R    = C / 4;          // lanes per head
    __shared__ float xs[32][Cin];
    int n0  = blockIdx.x * 32;
    int tid = threadIdx.x;
    // coalesced staging of 32 node rows (fp32 float4 or bf16 uint2 -> fp32 LDS)
    for (int i = tid; i < 32 * Cin / 4; i += 256) {
        int n = i / (Cin / 4), k4 = i % (Cin / 4);
        int gn = n0 + n;
        float4 v = make_float4(0.f, 0.f, 0.f, 0.f);
        if (gn < N_NODES) {
            if (IN_BF16) {
                uint2 q = ((const uint2*)((const unsigned short*)xin + (size_t)gn * Cin))[k4];
                v = make_float4(bf16_lo(q.x), bf16_hi(q.x), bf16_lo(q.y), bf16_hi(q.y));
            } else {
                v = ((const float4*)((const float*)xin + (size_t)gn * Cin))[k4];
            }
        }
        ((float4*)xs[n])[k4] = v;
    }
    __syncthreads();
    int oct  = tid % OCT;
    int nsub = tid / OCT;
    int head = oct / R;                  // this thread's head (channels 4-contig)
    int cin_head = (oct % R) * 4;        // channel offset within head
    float acc[NACC][OCP];
#pragma unroll
    for (int i = 0; i < NACC; i++)
#pragma unroll
        for (int j = 0; j < OCP; j++) acc[i][j] = 0.f;

#pragma unroll 4
    for (int k = 0; k < Cin; k++) {
        float4 wv = ((const float4*)(W + (size_t)k * Cout))[oct];
#pragma unroll
        for (int i = 0; i < NACC; i++) {
            float xv = xs[nsub * NACC + i][k];
            acc[i][0] += xv * wv.x; acc[i][1] += xv * wv.y;
            acc[i][2] += xv * wv.z; acc[i][3] += xv * wv.w;
        }
    }
    // load attention vectors for own 4 channels
    float4 av = ((const float4*)(a_src + head * C + cin_head))[0];
    float4 dv = ((const float4*)(a_dst + head * C + cin_head))[0];
#pragma unroll
    for (int i = 0; i < NACC; i++) {
        int gn = n0 + nsub * NACC + i;
        if (gn < N_NODES) {
            uint2 p;
            p.x = pack_bf16x2(acc[i][0], acc[i][1]);
            p.y = pack_bf16x2(acc[i][2], acc[i][3]);
            ((uint2*)hb)[((size_t)gn * Cout) / 4 + oct] = p;
        }
        // head-local logits reduction (R consecutive aligned lanes; gn uniform
        // within the shfl group, so no divergence hazard)
        float ps = acc[i][0] * av.x + acc[i][1] * av.y + acc[i][2] * av.z + acc[i][3] * av.w;
        float pd = acc[i][0] * dv.x + acc[i][1] * dv.y + acc[i][2] * dv.z + acc[i][3] * dv.w;
#pragma unroll
        for (int k = 1; k < R; k <<= 1) {
            ps += __shfl_xor(ps, k, 64);
            pd += __shfl_xor(pd, k, 64);
        }
        if ((oct % R) == 0 && gn < N_NODES) {
            al_s[gn * H + head] = ps;
            al_d[gn * H + head] = pd;
        }
    }
}

// ------------------------- GAT softmax + aggregation ------------------------
// One group of G = H*C/4 lanes per node; each lane owns 4 output channels
// (bf16 payload: one uint2 = 8 B per lane per edge). head = g/SUB.
// Phase 1: lane reduces ONLY its own head, edges strided by SUB; butterfly.
// Phase 2: uniform edge loop, batches of 8; no cross-lane ops; gather
//   addresses depend only on the batch's csr_src loads.
// OUT_BF16: intermediate feats written bf16; final layer writes fp32.
template<int H, int C, bool RELU, bool OUT_BF16>
__launch_bounds__(256, 8)
__global__ void gat_agg_kernel(const unsigned short* __restrict__ hb,
                               const float* __restrict__ al_s,
                               const float* __restrict__ al_d, const int* __restrict__ off,
                               const int* __restrict__ csr_src, const float* __restrict__ bias,
                               void* __restrict__ out) {
    constexpr int HC  = H * C;
    constexpr int G   = HC / 4;    // lanes per node (64 / 32 / 8)
    constexpr int SUB = G / H;     // lanes per head = edge-parallel width
    constexpr int NPW = 64 / G;    // nodes per wave
    constexpr int NPB = 4 * NPW;   // nodes per 256-thread block

    int tid  = threadIdx.x;
    int wid  = tid >> 6;
    int lane = tid & 63;
    int gi   = lane / G;           // node slot within wave
    int g    = lane % G;           // lane within node group
    int node = blockIdx.x * NPB + wid * NPW + gi;
    if (node >= N_NODES) return;

    int head = g / SUB;            // this lane's head
    int es   = g % SUB;            // edge-stride slot within head group
    int r0 = off[node], r1 = off[node + 1];
    float ald = al_d[node * H + head];

    // ---- phase 1: online softmax for OWN head, edges strided by SUB ----
    float m = -INFINITY, s = 0.f;
    for (int j = r0 + es; j < r1; j += SUB) {
        int src = csr_src[j];
        float e = al_s[src * H + head] + ald;
        e = (e > 0.f) ? e : 0.2f * e;
        float M = fmaxf(m, e);
        s = s * __expf(m - M) + __expf(e - M);
        m = M;
    }
#pragma unroll
    for (int k = 1; k < SUB; k <<= 1) {
        float om = __shfl_xor(m, k, 64);
        float os = __shfl_xor(s, k, 64);
        float M = fmaxf(m, om);
        float S;
        if (M == -INFINITY) S = 0.f;   // guard NaN from (-inf) - (-inf)
        else S = s * __expf(m - M) + os * __expf(om - M);
        m = M; s = S;
    }
    float inv_s = 1.f / s;             // s >= 1: every node has a self loop

    // ---- phase 2: uniform edge loop, batches of 8, no cross-lane ops ----
    const uint2* hb2 = (const uint2*)hb;
    float4 acc = ((const float4*)bias)[g];
    int j0 = r0;
    for (; j0 + 8 <= r1; j0 += 8) {
        int srcs[8];
#pragma unroll
        for (int u = 0; u < 8; u++) srcs[u] = csr_src[j0 + u];
#pragma unroll
        for (int u = 0; u < 8; u++) {
            float e = al_s[srcs[u] * H + head] + ald;
            e = (e > 0.f) ? e : 0.2f * e;
            float we = __expf(e - m) * inv_s;
            uint2 q = hb2[(size_t)srcs[u] * (HC / 4) + g];
            acc.x += we * bf16_lo(q.x); acc.y += we * bf16_hi(q.x);
            acc.z += we * bf16_lo(q.y); acc.w += we * bf16_hi(q.y);
        }
    }
    for (; j0 < r1; j0++) {
        int src = csr_src[j0];
        float e = al_s[src * H + head] + ald;
        e = (e > 0.f) ? e : 0.2f * e;
        float we = __expf(e - m) * inv_s;
        uint2 q = hb2[(size_t)src * (HC / 4) + g];
        acc.x += we * bf16_lo(q.x); acc.y += we * bf16_hi(q.x);
        acc.z += we * bf16_lo(q.y); acc.w += we * bf16_hi(q.y);
    }
    if (RELU) {
        acc.x = fmaxf(acc.x, 0.f); acc.y = fmaxf(acc.y, 0.f);
        acc.z = fmaxf(acc.z, 0.f); acc.w = fmaxf(acc.w, 0.f);
    }
    if (OUT_BF16) {
        uint2 p;
        p.x = pack_bf16x2(acc.x, acc.y);
        p.y = pack_bf16x2(acc.z, acc.w);
        ((uint2*)out)[(size_t)node * (HC / 4) + g] = p;
    } else {
        ((float4*)out)[(size_t)node * (HC / 4) + g] = acc;
    }
}

// ------------------------------- launcher -----------------------------------
extern "C" void kernel_launch(void* const* d_in, const int* in_sizes, int n_in,
                              void* d_out, int out_size, void* d_ws, size_t ws_size,
                              hipStream_t stream) {
    const float* x   = (const float*)d_in[0];
    const int*   ei  = (const int*)d_in[1];   // harness casts int64 -> int32
    const float* W1  = (const float*)d_in[2];
    const float* as1 = (const float*)d_in[3];
    const float* ad1 = (const float*)d_in[4];
    const float* b1  = (const float*)d_in[5];
    const float* W2  = (const float*)d_in[6];
    const float* as2 = (const float*)d_in[7];
    const float* ad2 = (const float*)d_in[8];
    const float* b2  = (const float*)d_in[9];
    const float* W3  = (const float*)d_in[10];
    const float* as3 = (const float*)d_in[11];
    const float* ad3 = (const float*)d_in[12];
    const float* b3  = (const float*)d_in[13];
    const float* W4  = (const float*)d_in[14];
    const float* as4 = (const float*)d_in[15];
    const float* ad4 = (const float*)d_in[16];
    const float* b4  = (const float*)d_in[17];

    char* ws = (char*)d_ws;
    size_t o = 0;
    auto alloc = [&](size_t bytes) -> void* {
        void* p = ws + o;
        o = (o + bytes + 255) & ~(size_t)255;
        return p;
    };
    unsigned short* feat_a  = (unsigned short*)alloc((size_t)N_NODES * 256 * 2); // 25.6 MB bf16
    unsigned short* feat_b  = (unsigned short*)alloc((size_t)N_NODES * 32 * 2);  // 3.2 MB bf16
    unsigned short* h_buf   = (unsigned short*)alloc((size_t)N_NODES * 256 * 2); // 25.6 MB bf16
    float*          al_s    = (float*)alloc((size_t)N_NODES * 8 * 4);
    float*          al_d    = (float*)alloc((size_t)N_NODES * 8 * 4);
    int*            deg     = (int*)alloc((size_t)(N_NODES + 1) * 4);
    int*            off     = (int*)alloc((size_t)(N_NODES + 1) * 4);
    int*            cursor  = (int*)alloc((size_t)N_NODES * 4);
    int*            part    = (int*)alloc((size_t)N_NODES * 4);
    int*            bsum    = (int*)alloc((size_t)256 * 4);
    int*            csr_src = (int*)alloc((size_t)N_TOT * 4);

    const int TPB = 256;
    int nb_nodes = (N_NODES + TPB - 1) / TPB;   // = NSB
    int nb_edges = (N_TOT + TPB - 1) / TPB;
    int nb_gemm  = (N_NODES + 31) / 32;

    // ---- CSR build (by dst), parallel scan ----
    zero_int_kernel<<<nb_nodes, TPB, 0, stream>>>(deg, N_NODES);
    deg_hist_kernel<<<nb_edges, TPB, 0, stream>>>(ei, deg);
    block_scan_kernel<<<NSB, TPB, 0, stream>>>(deg, part, bsum);
    scan_bsum_kernel<<<1, TPB, 0, stream>>>(bsum);
    finalize_off_kernel<<<NSB, TPB, 0, stream>>>(part, bsum, off, cursor);
    fill_csr_kernel<<<nb_edges, TPB, 0, stream>>>(ei, cursor, csr_src);

    auto agg_blocks = [](int hc) { return (N_NODES * (hc / 4) + 255) / 256; };

    // ---- Layer 1: 128 -> (8 heads x 32), ReLU ----
    gemm_fused_kernel<128, 256, 8, 32, false><<<nb_gemm, TPB, 0, stream>>>(x, W1, as1, ad1, h_buf, al_s, al_d);
    gat_agg_kernel<8, 32, true, true><<<agg_blocks(256), TPB, 0, stream>>>(h_buf, al_s, al_d, off, csr_src, b1, feat_a);

    // ---- Layer 2: 256 -> 32, 1 head ----
    gemm_fused_kernel<256, 32, 1, 32, true><<<nb_gemm, TPB, 0, stream>>>(feat_a, W2, as2, ad2, h_buf, al_s, al_d);
    gat_agg_kernel<1, 32, false, true><<<agg_blocks(32), TPB, 0, stream>>>(h_buf, al_s, al_d, off, csr_src, b2, feat_b);

    // ---- Layer 3: 32 -> (8 heads x 32), ReLU ----
    gemm_fused_kernel<32, 256, 8, 32, true><<<nb_gemm, TPB, 0, stream>>>(feat_b, W3, as3, ad3, h_buf, al_s, al_d);
    gat_agg_kernel<8, 32, true, true><<<agg_blocks(256), TPB, 0, stream>>>(h_buf, al_s, al_d, off, csr_src, b3, feat_a);

    // ---- Layer 4: 256 -> 128, 1 head ----
    gemm_fused_kernel<256, 128, 1, 128, true><<<nb_gemm, TPB, 0, stream>>>(feat_a, W4, as4, ad4, h_buf, al_s, al_d);
    gat_agg_kernel<1, 128, false, false><<<agg_blocks(128), TPB, 0, stream>>>(h_buf, al_s, al_d, off, csr_src, b4, d_out);
}

// Round 10
// 541.854 us; speedup vs baseline: 1.6554x; 1.1907x over previous
//
#include <hip/hip_runtime.h>
#include <math.h>

#define N_NODES 50000
#define N_EDGES 800000
#define N_TOT   850000   // edges + self loops
#define NSB     ((N_NODES + 255) / 256)   // scan blocks = 196

typedef __attribute__((ext_vector_type(8))) short short8;   // 8 bf16 (4 VGPRs)
typedef __attribute__((ext_vector_type(4))) float floatx4;  // MFMA acc

// ---------------------------- bf16 pack/unpack ------------------------------
__device__ __forceinline__ unsigned int pack_bf16x2(float a, float b) {
    unsigned ua = __float_as_uint(a);
    unsigned ub = __float_as_uint(b);
    ua += 0x7fff + ((ua >> 16) & 1);   // round-to-nearest-even
    ub += 0x7fff + ((ub >> 16) & 1);
    return (ua >> 16) | (ub & 0xffff0000u);
}
__device__ __forceinline__ unsigned short pack_bf16(float a) {
    unsigned ua = __float_as_uint(a);
    ua += 0x7fff + ((ua >> 16) & 1);
    return (unsigned short)(ua >> 16);
}
__device__ __forceinline__ float bf16_lo(unsigned u) { return __uint_as_float(u << 16); }
__device__ __forceinline__ float bf16_hi(unsigned u) { return __uint_as_float(u & 0xffff0000u); }

// ----------------------------- utility kernels -----------------------------
__global__ void zero_int_kernel(int* p, int n) {
    int i = blockIdx.x * blockDim.x + threadIdx.x;
    if (i < n) p[i] = 0;
}

// ----------------------------- CSR build -----------------------------------
__global__ void deg_hist_kernel(const int* __restrict__ ei, int* __restrict__ deg) {
    int e = blockIdx.x * blockDim.x + threadIdx.x;
    if (e >= N_TOT) return;
    int dst = (e < N_EDGES) ? ei[N_EDGES + e] : (e - N_EDGES);
    atomicAdd(&deg[dst], 1);
}

__global__ void block_scan_kernel(const int* __restrict__ deg, int* __restrict__ part,
                                  int* __restrict__ bsum) {
    __shared__ int tmp[256];
    int t = threadIdx.x;
    int i = blockIdx.x * 256 + t;
    int v = (i < N_NODES) ? deg[i] : 0;
    tmp[t] = v;
    __syncthreads();
    for (int d = 1; d < 256; d <<= 1) {
        int u = (t >= d) ? tmp[t - d] : 0;
        __syncthreads();
        tmp[t] += u;
        __syncthreads();
    }
    if (i < N_NODES) part[i] = tmp[t] - v;   // exclusive
    if (t == 255) bsum[blockIdx.x] = tmp[255];
}

__global__ void scan_bsum_kernel(int* __restrict__ bsum) {
    __shared__ int tmp[256];
    int t = threadIdx.x;
    int v = (t < NSB) ? bsum[t] : 0;
    tmp[t] = v;
    __syncthreads();
    for (int d = 1; d < 256; d <<= 1) {
        int u = (t >= d) ? tmp[t - d] : 0;
        __syncthreads();
        tmp[t] += u;
        __syncthreads();
    }
    if (t < NSB) bsum[t] = tmp[t] - v;       // exclusive block offsets
}

__global__ void finalize_off_kernel(const int* __restrict__ part, const int* __restrict__ bsum,
                                    int* __restrict__ off, int* __restrict__ cursor) {
    int i = blockIdx.x * 256 + threadIdx.x;
    if (i < N_NODES) {
        int o = part[i] + bsum[blockIdx.x];
        off[i] = o;
        cursor[i] = o;
    }
    if (i == 0) off[N_NODES] = N_TOT;
}

__global__ void fill_csr_kernel(const int* __restrict__ ei, int* __restrict__ cursor,
                                int* __restrict__ csr_src) {
    int e = blockIdx.x * blockDim.x + threadIdx.x;
    if (e >= N_TOT) return;
    int src, dst;
    if (e < N_EDGES) { src = ei[e]; dst = ei[N_EDGES + e]; }
    else             { src = dst = e - N_EDGES; }
    int pos = atomicAdd(&cursor[dst], 1);
    csr_src[pos] = src;
}

// --------------- weight convert: W [K][N] fp32 -> Wt [N][K] bf16 ------------
__global__ void wconv_kernel(const float* __restrict__ W1, const float* __restrict__ W2,
                             const float* __restrict__ W3, const float* __restrict__ W4,
                             unsigned short* __restrict__ T1, unsigned short* __restrict__ T2,
                             unsigned short* __restrict__ T3, unsigned short* __restrict__ T4) {
    int i = blockIdx.x * 256 + threadIdx.x;
    const float* W; unsigned short* T; int K, N, idx;
    if      (i < 32768) { W = W1; T = T1; K = 128; N = 256; idx = i; }
    else if (i < 40960) { W = W2; T = T2; K = 256; N = 32;  idx = i - 32768; }
    else if (i < 49152) { W = W3; T = T3; K = 32;  N = 256; idx = i - 40960; }
    else if (i < 81920) { W = W4; T = T4; K = 256; N = 128; idx = i - 49152; }
    else return;
    int n = idx / K, k = idx % K;
    T[idx] = pack_bf16(W[(size_t)k * N + n]);
}

// ------------------ fused MFMA GEMM + attention logits ----------------------
// Block = 256 threads (4 waves), covers NPB nodes x Cout channels.
// A (nodes x Cin) staged to LDS bf16 (row pad +8 elems -> conflict-free
// ds_read_b128 fragments). B read from Wt [Cout][Cin] bf16 (global, L2-hot).
// Wave w: m-tiles (w/NW_N), n-tiles (w%NW_N); 16x16x32 bf16 MFMA K-loop.
// Epilogue: C -> padded LDS (fp32), then thread-per-(node, 32ch chunk):
// al_s/al_d dots (shfl-reduce across chunks if C>32), bf16 h pack, coalesced
// uint4 stores.
template<int Cin, int Cout, int H, int C, int NPB, int NW_N, bool IN_BF16>
__global__ void gemm_mfma_kernel(const void* __restrict__ xin,
                                 const unsigned short* __restrict__ Wt,
                                 const float* __restrict__ a_src, const float* __restrict__ a_dst,
                                 unsigned short* __restrict__ hb,
                                 float* __restrict__ al_s, float* __restrict__ al_d) {
    constexpr int NW_M = 4 / NW_N;
    constexpr int MT_W = (NPB / 16) / NW_M;   // m-tiles per wave
    constexpr int NT_W = (Cout / 16) / NW_N;  // n-tiles per wave
    constexpr int AS   = Cin + 8;             // A row stride (bf16 elems)
    constexpr int SP   = Cout + 4;            // hs row stride (floats)
    __shared__ unsigned short xs[NPB * AS];
    __shared__ float hs[NPB * SP];
    int tid = threadIdx.x;
    int n0  = blockIdx.x * NPB;

    // ---- stage A tile as bf16 ----
    if (IN_BF16) {
        for (int i = tid; i < NPB * Cin / 8; i += 256) {
            int n = i / (Cin / 8), k8 = i % (Cin / 8);
            uint4 q = make_uint4(0u, 0u, 0u, 0u);
            if (n0 + n < N_NODES)
                q = ((const uint4*)((const unsigned short*)xin + (size_t)(n0 + n) * Cin))[k8];
            *(uint4*)(xs + n * AS + k8 * 8) = q;
        }
    } else {
        for (int i = tid; i < NPB * Cin / 4; i += 256) {
            int n = i / (Cin / 4), k4 = i % (Cin / 4);
            float4 v = make_float4(0.f, 0.f, 0.f, 0.f);
            if (n0 + n < N_NODES)
                v = ((const float4*)((const float*)xin + (size_t)(n0 + n) * Cin))[k4];
            uint2 p;
            p.x = pack_bf16x2(v.x, v.y);
            p.y = pack_bf16x2(v.z, v.w);
            *(uint2*)(xs + n * AS + k4 * 4) = p;
        }
    }
    __syncthreads();

    int w = tid >> 6, lane = tid & 63;
    int q = lane >> 4, l16 = lane & 15;
    int wm = w / NW_N, wn = w % NW_N;
    int mbase = wm * MT_W * 16;
    int nbase = wn * NT_W * 16;

    floatx4 acc[MT_W][NT_W];
#pragma unroll
    for (int mt = 0; mt < MT_W; mt++)
#pragma unroll
        for (int nt = 0; nt < NT_W; nt++) acc[mt][nt] = (floatx4){0.f, 0.f, 0.f, 0.f};

#pragma unroll
    for (int k0 = 0; k0 < Cin; k0 += 32) {
        short8 a[MT_W], b[NT_W];
#pragma unroll
        for (int mt = 0; mt < MT_W; mt++)
            a[mt] = *(const short8*)(xs + (mbase + mt * 16 + l16) * AS + k0 + q * 8);
#pragma unroll
        for (int nt = 0; nt < NT_W; nt++)
            b[nt] = *(const short8*)(Wt + (size_t)(nbase + nt * 16 + l16) * Cin + k0 + q * 8);
#pragma unroll
        for (int mt = 0; mt < MT_W; mt++)
#pragma unroll
            for (int nt = 0; nt < NT_W; nt++)
                acc[mt][nt] = __builtin_amdgcn_mfma_f32_16x16x32_bf16(a[mt], b[nt], acc[mt][nt], 0, 0, 0);
    }

    // ---- C tiles -> LDS (row = q*4 + reg, col = l16; verified layout) ----
#pragma unroll
    for (int mt = 0; mt < MT_W; mt++)
#pragma unroll
        for (int nt = 0; nt < NT_W; nt++)
#pragma unroll
            for (int r = 0; r < 4; r++) {
                int nl = mbase + mt * 16 + q * 4 + r;
                int ch = nbase + nt * 16 + l16;
                hs[nl * SP + ch] = acc[mt][nt][r];
            }
    __syncthreads();

    // ---- epilogue: logits + bf16 h write ----
    constexpr int TPN = Cout / 32;            // threads per node (32 ch each)
    constexpr int TPH = (C > 32) ? (C / 32) : 1;  // threads sharing one head
    if (tid < NPB * TPN) {
        int node = tid / TPN, sub = tid % TPN;
        int gn = n0 + node;
        int head = (sub * 32) / C;
        int coff = (sub * 32) % C;
        const float* hrow = hs + node * SP + sub * 32;
        const float* ap = a_src + head * C + coff;
        const float* dp = a_dst + head * C + coff;
        float ps = 0.f, pd = 0.f;
        unsigned pk[8];
#pragma unroll
        for (int c4 = 0; c4 < 8; c4++) {
            float4 hv = *(const float4*)(hrow + c4 * 4);
            float4 av = *(const float4*)(ap + c4 * 4);
            float4 dv = *(const float4*)(dp + c4 * 4);
            ps += hv.x * av.x + hv.y * av.y + hv.z * av.z + hv.w * av.w;
            pd += hv.x * dv.x + hv.y * dv.y + hv.z * dv.z + hv.w * dv.w;
            pk[c4] = pack_bf16x2(hv.x, hv.y) | 0u;  // low pair
            // store both pairs: pack into two u32 slots
            pk[c4] = pack_bf16x2(hv.x, hv.y);
            // second pair handled below via separate array slot
        }
        // repack properly: 32 bf16 = 16 u32
        uint4 o0, o1;
        {
            float4 h0 = *(const float4*)(hrow + 0);
            float4 h1 = *(const float4*)(hrow + 4);
            float4 h2 = *(const float4*)(hrow + 8);
            float4 h3 = *(const float4*)(hrow + 12);
            o0.x = pack_bf16x2(h0.x, h0.y); o0.y = pack_bf16x2(h0.z, h0.w);
            o0.z = pack_bf16x2(h1.x, h1.y); o0.w = pack_bf16x2(h1.z, h1.w);
            o1.x = pack_bf16x2(h2.x, h2.y); o1.y = pack_bf16x2(h2.z, h2.w);
            o1.z = pack_bf16x2(h3.x, h3.y); o1.w = pack_bf16x2(h3.z, h3.w);
        }
        uint4 o2, o3;
        {
            float4 h0 = *(const float4*)(hrow + 16);
            float4 h1 = *(const float4*)(hrow + 20);
            float4 h2 = *(const float4*)(hrow + 24);
            float4 h3 = *(const float4*)(hrow + 28);
            o2.x = pack_bf16x2(h0.x, h0.y); o2.y = pack_bf16x2(h0.z, h0.w);
            o2.z = pack_bf16x2(h1.x, h1.y); o2.w = pack_bf16x2(h1.z, h1.w);
            o3.x = pack_bf16x2(h2.x, h2.y); o3.y = pack_bf16x2(h2.z, h2.w);
            o3.z = pack_bf16x2(h3.x, h3.y); o3.w = pack_bf16x2(h3.z, h3.w);
        }
        if (gn < N_NODES) {
            uint2* dst = (uint2*)(hb + (size_t)gn * Cout + sub * 32);
            dst[0] = make_uint2(o0.x, o0.y); dst[1] = make_uint2(o0.z, o0.w);
            dst[2] = make_uint2(o1.x, o1.y); dst[3] = make_uint2(o1.z, o1.w);
            dst[4] = make_uint2(o2.x, o2.y); dst[5] = make_uint2(o2.z, o2.w);
            dst[6] = make_uint2(o3.x, o3.y); dst[7] = make_uint2(o3.z, o3.w);
        }
        if (TPH > 1) {
#pragma unroll
            for (int k = 1; k < TPH; k <<= 1) {
                ps += __shfl_xor(ps, k, 64);
                pd += __shfl_xor(pd, k, 64);
            }
            if ((sub % TPH) == 0 && gn < N_NODES) {
                al_s[gn * H + head] = ps;
                al_d[gn * H + head] = pd;
            }
        } else {
            if (gn < N_NODES) {
                al_s[gn * H + head] = ps;
                al_d[gn * H + head] = pd;
            }
        }
    }
}

// ------------------------- GAT softmax + aggregation ------------------------
template<int H, int C, bool RELU, bool OUT_BF16>
__launch_bounds__(256, 8)
__global__ void gat_agg_kernel(const unsigned short* __restrict__ hb,
                               const float* __restrict__ al_s,
                               const float* __restrict__ al_d, const int* __restrict__ off,
                               const int* __restrict__ csr_src, const float* __restrict__ bias,
                               void* __restrict__ out) {
    constexpr int HC  = H * C;
    constexpr int G   = HC / 4;    // lanes per node (64 / 32 / 8)
    constexpr int SUB = G / H;     // lanes per head = edge-parallel width
    constexpr int NPW = 64 / G;    // nodes per wave
    constexpr int NPB = 4 * NPW;   // nodes per 256-thread block

    int tid  = threadIdx.x;
    int wid  = tid >> 6;
    int lane = tid & 63;
    int gi   = lane / G;           // node slot within wave
    int g    = lane % G;           // lane within node group
    int node = blockIdx.x * NPB + wid * NPW + gi;
    if (node >= N_NODES) return;

    int head = g / SUB;            // this lane's head
    int es   = g % SUB;            // edge-stride slot within head group
    int r0 = off[node], r1 = off[node + 1];
    float ald = al_d[node * H + head];

    // ---- phase 1: online softmax for OWN head, edges strided by SUB ----
    float m = -INFINITY, s = 0.f;
    for (int j = r0 + es; j < r1; j += SUB) {
        int src = csr_src[j];
        float e = al_s[src * H + head] + ald;
        e = (e > 0.f) ? e : 0.2f * e;
        float M = fmaxf(m, e);
        s = s * __expf(m - M) + __expf(e - M);
        m = M;
    }
#pragma unroll
    for (int k = 1; k < SUB; k <<= 1) {
        float om = __shfl_xor(m, k, 64);
        float os = __shfl_xor(s, k, 64);
        float M = fmaxf(m, om);
        float S;
        if (M == -INFINITY) S = 0.f;   // guard NaN from (-inf) - (-inf)
        else S = s * __expf(m - M) + os * __expf(om - M);
        m = M; s = S;
    }
    float inv_s = 1.f / s;             // s >= 1: every node has a self loop

    // ---- phase 2: uniform edge loop, batches of 8, no cross-lane ops ----
    const uint2* hb2 = (const uint2*)hb;
    float4 acc = ((const float4*)bias)[g];
    int j0 = r0;
    for (; j0 + 8 <= r1; j0 += 8) {
        int srcs[8];
#pragma unroll
        for (int u = 0; u < 8; u++) srcs[u] = csr_src[j0 + u];
#pragma unroll
        for (int u = 0; u < 8; u++) {
            float e = al_s[srcs[u] * H + head] + ald;
            e = (e > 0.f) ? e : 0.2f * e;
            float we = __expf(e - m) * inv_s;
            uint2 q = hb2[(size_t)srcs[u] * (HC / 4) + g];
            acc.x += we * bf16_lo(q.x); acc.y += we * bf16_hi(q.x);
            acc.z += we * bf16_lo(q.y); acc.w += we * bf16_hi(q.y);
        }
    }
    for (; j0 < r1; j0++) {
        int src = csr_src[j0];
        float e = al_s[src * H + head] + ald;
        e = (e > 0.f) ? e : 0.2f * e;
        float we = __expf(e - m) * inv_s;
        uint2 q = hb2[(size_t)src * (HC / 4) + g];
        acc.x += we * bf16_lo(q.x); acc.y += we * bf16_hi(q.x);
        acc.z += we * bf16_lo(q.y); acc.w += we * bf16_hi(q.y);
    }
    if (RELU) {
        acc.x = fmaxf(acc.x, 0.f); acc.y = fmaxf(acc.y, 0.f);
        acc.z = fmaxf(acc.z, 0.f); acc.w = fmaxf(acc.w, 0.f);
    }
    if (OUT_BF16) {
        uint2 p;
        p.x = pack_bf16x2(acc.x, acc.y);
        p.y = pack_bf16x2(acc.z, acc.w);
        ((uint2*)out)[(size_t)node * (HC / 4) + g] = p;
    } else {
        ((float4*)out)[(size_t)node * (HC / 4) + g] = acc;
    }
}

// ------------------------------- launcher -----------------------------------
extern "C" void kernel_launch(void* const* d_in, const int* in_sizes, int n_in,
                              void* d_out, int out_size, void* d_ws, size_t ws_size,
                              hipStream_t stream) {
    const float* x   = (const float*)d_in[0];
    const int*   ei  = (const int*)d_in[1];   // harness casts int64 -> int32
    const float* W1  = (const float*)d_in[2];
    const float* as1 = (const float*)d_in[3];
    const float* ad1 = (const float*)d_in[4];
    const float* b1  = (const float*)d_in[5];
    const float* W2  = (const float*)d_in[6];
    const float* as2 = (const float*)d_in[7];
    const float* ad2 = (const float*)d_in[8];
    const float* b2  = (const float*)d_in[9];
    const float* W3  = (const float*)d_in[10];
    const float* as3 = (const float*)d_in[11];
    const float* ad3 = (const float*)d_in[12];
    const float* b3  = (const float*)d_in[13];
    const float* W4  = (const float*)d_in[14];
    const float* as4 = (const float*)d_in[15];
    const float* ad4 = (const float*)d_in[16];
    const float* b4  = (const float*)d_in[17];

    char* ws = (char*)d_ws;
    size_t o = 0;
    auto alloc = [&](size_t bytes) -> void* {
        void* p = ws + o;
        o = (o + bytes + 255) & ~(size_t)255;
        return p;
    };
    unsigned short* feat_a  = (unsigned short*)alloc((size_t)N_NODES * 256 * 2); // 25.6 MB bf16
    unsigned short* feat_b  = (unsigned short*)alloc((size_t)N_NODES * 32 * 2);  // 3.2 MB bf16
    unsigned short* h_buf   = (unsigned short*)alloc((size_t)N_NODES * 256 * 2); // 25.6 MB bf16
    float*          al_s    = (float*)alloc((size_t)N_NODES * 8 * 4);
    float*          al_d    = (float*)alloc((size_t)N_NODES * 8 * 4);
    int*            deg     = (int*)alloc((size_t)(N_NODES + 1) * 4);
    int*            off     = (int*)alloc((size_t)(N_NODES + 1) * 4);
    int*            cursor  = (int*)alloc((size_t)N_NODES * 4);
    int*            part    = (int*)alloc((size_t)N_NODES * 4);
    int*            bsum    = (int*)alloc((size_t)256 * 4);
    int*            csr_src = (int*)alloc((size_t)N_TOT * 4);
    unsigned short* w1t     = (unsigned short*)alloc(32768 * 2);  // [256][128]
    unsigned short* w2t     = (unsigned short*)alloc(8192 * 2);   // [32][256]
    unsigned short* w3t     = (unsigned short*)alloc(8192 * 2);   // [256][32]
    unsigned short* w4t     = (unsigned short*)alloc(32768 * 2);  // [128][256]

    const int TPB = 256;
    int nb_nodes = (N_NODES + TPB - 1) / TPB;   // = NSB
    int nb_edges = (N_TOT + TPB - 1) / TPB;

    // ---- CSR build (by dst), parallel scan; weight convert ----
    zero_int_kernel<<<nb_nodes, TPB, 0, stream>>>(deg, N_NODES);
    wconv_kernel<<<320, TPB, 0, stream>>>(W1, W2, W3, W4, w1t, w2t, w3t, w4t);
    deg_hist_kernel<<<nb_edges, TPB, 0, stream>>>(ei, deg);
    block_scan_kernel<<<NSB, TPB, 0, stream>>>(deg, part, bsum);
    scan_bsum_kernel<<<1, TPB, 0, stream>>>(bsum);
    finalize_off_kernel<<<NSB, TPB, 0, stream>>>(part, bsum, off, cursor);
    fill_csr_kernel<<<nb_edges, TPB, 0, stream>>>(ei, cursor, csr_src);

    auto agg_blocks = [](int hc) { return (N_NODES * (hc / 4) + 255) / 256; };

    // ---- Layer 1: 128 -> (8 heads x 32), ReLU ----
    gemm_mfma_kernel<128, 256, 8, 32, 32, 4, false>
        <<<(N_NODES + 31) / 32, TPB, 0, stream>>>(x, w1t, as1, ad1, h_buf, al_s, al_d);
    gat_agg_kernel<8, 32, true, true><<<agg_blocks(256), TPB, 0, stream>>>(h_buf, al_s, al_d, off, csr_src, b1, feat_a);

    // ---- Layer 2: 256 -> 32, 1 head ----
    gemm_mfma_kernel<256, 32, 1, 32, 64, 2, true>
        <<<(N_NODES + 63) / 64, TPB, 0, stream>>>(feat_a, w2t, as2, ad2, h_buf, al_s, al_d);
    gat_agg_kernel<1, 32, false, true><<<agg_blocks(32), TPB, 0, stream>>>(h_buf, al_s, al_d, off, csr_src, b2, feat_b);

    // ---- Layer 3: 32 -> (8 heads x 32), ReLU ----
    gemm_mfma_kernel<32, 256, 8, 32, 32, 4, true>
        <<<(N_NODES + 31) / 32, TPB, 0, stream>>>(feat_b, w3t, as3, ad3, h_buf, al_s, al_d);
    gat_agg_kernel<8, 32, true, true><<<agg_blocks(256), TPB, 0, stream>>>(h_buf, al_s, al_d, off, csr_src, b3, feat_a);

    // ---- Layer 4: 256 -> 128, 1 head ----
    gemm_mfma_kernel<256, 128, 1, 128, 32, 4, true>
        <<<(N_NODES + 31) / 32, TPB, 0, stream>>>(feat_a, w4t, as4, ad4, h_buf, al_s, al_d);
    gat_agg_kernel<1, 128, false, false><<<agg_blocks(128), TPB, 0, stream>>>(h_buf, al_s, al_d, off, csr_src, b4, d_out);
}